// Round 10
// baseline (139.319 us; speedup 1.0000x reference)
//
#include <hip/hip_runtime.h>
#include <hip/hip_bf16.h>
#include <cstdint>

#define B_ 2
#define S_ 2048
#define D_ 1024
#define H_ 16
#define DK_ 64

typedef __bf16 bf16x8 __attribute__((ext_vector_type(8)));
typedef float f32x4 __attribute__((ext_vector_type(4)));
typedef unsigned int u32x4 __attribute__((ext_vector_type(4)));

typedef __attribute__((address_space(3))) void lds_void_t;
typedef const __attribute__((address_space(1))) void gbl_void_t;

__device__ __forceinline__ unsigned short f2bf(float x) {
    unsigned int u = __builtin_bit_cast(unsigned int, x);
    u += 0x7fffu + ((u >> 16) & 1u);
    return (unsigned short)(u >> 16);
}

__device__ __forceinline__ float exp2fast(float x) {
    float r;
    asm("v_exp_f32 %0, %1" : "=v"(r) : "v"(x));
    return r;
}

__device__ __forceinline__ unsigned cvtpk(float a, float b) {
    unsigned r;
    asm("v_cvt_pk_bf16_f32 %0, %1, %2" : "=v"(r) : "v"(a), "v"(b));
    return r;
}

__device__ __forceinline__ void gload16(const void* g, void* lds) {
    __builtin_amdgcn_global_load_lds((gbl_void_t*)(uintptr_t)g,
                                     (lds_void_t*)(unsigned)(uintptr_t)lds,
                                     16, 0, 0);
}

__device__ __forceinline__ bf16x8 lds_read8(const unsigned short* p) {
    return __builtin_bit_cast(bf16x8, *(const u32x4*)p);
}

__device__ __forceinline__ f32x4 mfma16(bf16x8 a, bf16x8 b, f32x4 c) {
    return __builtin_amdgcn_mfma_f32_16x16x32_bf16(a, b, c, 0, 0, 0);
}

// ------- prep: cast+transpose W [K][N] fp32 -> Wt [N][K] bf16 (4 W's, x-decoded) -------
__global__ void prep_w_kernel(const float* __restrict__ Wq, const float* __restrict__ Wk,
                              const float* __restrict__ Wv, const float* __restrict__ Wo,
                              unsigned short* __restrict__ WqT, unsigned short* __restrict__ WkT,
                              unsigned short* __restrict__ WvT, unsigned short* __restrict__ WoT) {
    const int wsel = blockIdx.x >> 10;
    const int rem  = blockIdx.x & 1023;
    const int bx = rem & 31, by = rem >> 5;
    const float* W = (wsel == 0) ? Wq : (wsel == 1) ? Wk : (wsel == 2) ? Wv : Wo;
    unsigned short* Wt = (wsel == 0) ? WqT : (wsel == 1) ? WkT : (wsel == 2) ? WvT : WoT;
    __shared__ float t[32][33];
    const int tx = threadIdx.x & 31, ty = threadIdx.x >> 5;
#pragma unroll
    for (int j = 0; j < 4; j++)
        t[ty + 8 * j][tx] = W[(size_t)(by * 32 + ty + 8 * j) * D_ + bx * 32 + tx];
    __syncthreads();
#pragma unroll
    for (int j = 0; j < 4; j++)
        Wt[(size_t)(bx * 32 + ty + 8 * j) * D_ + by * 32 + tx] = f2bf(t[tx][ty + 8 * j]);
}

// -------- fused QKV projection GEMM with in-kernel fp32->bf16 A-cast, z selects --------
// z=0: qb  <- Q@WqT + bq, scaled by qs, layout [B][H][S][DK]
// z=1: kb  <- K@WkT + bk,               layout [B][H][S][DK]
// z=2: vTb <- V@WvT + bv,               layout [B][H][DK][S] (LDS-transposed, coalesced)
__global__ __launch_bounds__(256, 3) void qkv_gemm(
    const float* __restrict__ Qf, const float* __restrict__ Kf,
    const float* __restrict__ Vf, const unsigned short* __restrict__ WqT,
    const unsigned short* __restrict__ WkT, const unsigned short* __restrict__ WvT,
    const float* __restrict__ bq, const float* __restrict__ bk,
    const float* __restrict__ bvv, unsigned short* __restrict__ qb,
    unsigned short* __restrict__ kb, unsigned short* __restrict__ vTb, float qs) {
    constexpr int Kd = 1024;
    __shared__ __align__(16) unsigned short As[128 * 32];
    __shared__ __align__(16) unsigned short Bs[128 * 32];
    __shared__ __align__(16) unsigned short Cs[128 * 136];  // z==2 transpose staging
    const int z = blockIdx.z;
    const float* Af = (z == 0) ? Qf : (z == 1) ? Kf : Vf;
    const unsigned short* Bt = (z == 0) ? WqT : (z == 1) ? WkT : WvT;
    const float* bias = (z == 0) ? bq : (z == 1) ? bk : bvv;
    const float cscale = (z == 0) ? qs : 1.0f;

    const int tid = threadIdx.x;
    const int l = tid & 63, w = tid >> 6;
    const int lr = l & 15, g = l >> 4;
    const int wr = w & 1, wc = w >> 1;
    const int m0 = blockIdx.y * 128, n0 = blockIdx.x * 128;

    f32x4 acc[4][4] = {};

    // A reg-staging geometry: thread covers rows arow+32i, cols acol..acol+3 (fp32)
    const int arow = tid >> 3;            // 0..31
    const int acol = (tid & 3) * 8 + ((tid >> 2) & 1) * 4;  // 0,4,..28 spread
    const float* a_base = Af + (size_t)(m0 + arow) * Kd + acol;

    // B staging geometry (gload16 from bf16 W^T)
    const int mr = tid >> 2;
    const int kk = (tid & 3) * 8;
    const unsigned short* b_src = Bt + (size_t)(n0 + mr) * Kd + kk;
    char* bsb = (char*)Bs + w * 1024;

    // preload A regs for k0 = 0
    float4 areg[4];
#pragma unroll
    for (int i = 0; i < 4; i++)
        areg[i] = *reinterpret_cast<const float4*>(a_base + (size_t)(32 * i) * Kd);

    for (int k0 = 0; k0 < Kd; k0 += 32) {
        __syncthreads();  // [1] prev compute done (As writable); drains A prefetch
        gload16(b_src + k0,           bsb);
        gload16(b_src + 64 * Kd + k0, bsb + 4096);
#pragma unroll
        for (int i = 0; i < 4; i++) {
            uint2 pk;
            pk.x = cvtpk(areg[i].x, areg[i].y);
            pk.y = cvtpk(areg[i].z, areg[i].w);
            *reinterpret_cast<uint2*>(&As[(arow + 32 * i) * 32 + acol]) = pk;
        }
        __syncthreads();  // [2] drains B gload (vmcnt) + A ds_writes (lgkm)
        if (k0 + 32 < Kd) {  // prefetch next A regs; latency hides under MFMA phase
#pragma unroll
            for (int i = 0; i < 4; i++)
                areg[i] = *reinterpret_cast<const float4*>(
                    a_base + (size_t)(32 * i) * Kd + k0 + 32);
        }
        bf16x8 av[4], bv[4];
#pragma unroll
        for (int mi = 0; mi < 4; mi++)
            av[mi] = lds_read8(&As[(wr * 64 + mi * 16 + lr) * 32 + g * 8]);
#pragma unroll
        for (int ni = 0; ni < 4; ni++)
            bv[ni] = lds_read8(&Bs[(wc * 64 + ni * 16 + lr) * 32 + g * 8]);
#pragma unroll
        for (int mi = 0; mi < 4; mi++)
#pragma unroll
            for (int ni = 0; ni < 4; ni++)
                acc[mi][ni] = mfma16(av[mi], bv[ni], acc[mi][ni]);
    }

    if (z == 2) {
        // stage tile into Cs[col(dk)][row(s)], 136-elem stride (16B-aligned rows)
#pragma unroll
        for (int ni = 0; ni < 4; ni++) {
            const int cl = wc * 64 + ni * 16 + lr;
            const float bcol = bias[n0 + cl];
#pragma unroll
            for (int mi = 0; mi < 4; mi++) {
                const int rw = wr * 64 + mi * 16 + 4 * g;
                uint2 pk;
                pk.x = cvtpk(acc[mi][ni][0] + bcol, acc[mi][ni][1] + bcol);
                pk.y = cvtpk(acc[mi][ni][2] + bcol, acc[mi][ni][3] + bcol);
                *reinterpret_cast<uint2*>(&Cs[cl * 136 + rw]) = pk;
            }
        }
        __syncthreads();
        const int s0g = m0 & 2047;
        const int bb  = m0 >> 11;
#pragma unroll
        for (int it = 0; it < 8; ++it) {
            const int cl = it * 16 + (tid >> 4);
            const int sc = tid & 15;
            const int cg = n0 + cl;
            const int hh = cg >> 6, dk = cg & 63;
            const u32x4 vv = *reinterpret_cast<const u32x4*>(&Cs[cl * 136 + sc * 8]);
            *reinterpret_cast<u32x4*>(
                &vTb[(((size_t)(bb * H_ + hh) * DK_ + dk) << 11) + s0g + sc * 8]) = vv;
        }
    } else {
#pragma unroll
        for (int ni = 0; ni < 4; ni++) {
            const int col = n0 + wc * 64 + ni * 16 + lr;
            const float bcol = bias[col];
#pragma unroll
            for (int mi = 0; mi < 4; mi++) {
#pragma unroll
                for (int r = 0; r < 4; r++) {
                    const int row = m0 + wr * 64 + mi * 16 + 4 * g + r;
                    const float v = (acc[mi][ni][r] + bcol) * cscale;
                    const int b = row >> 11, s = row & 2047, h = col >> 6, dk = col & 63;
                    unsigned short* out = z ? kb : qb;
                    out[(((size_t)(b * H_ + h) * S_ + s) << 6) + dk] = f2bf(v);
                }
            }
        }
    }
}

// ---------------- out-projection GEMM: fp32 out row-major ----------------
__global__ __launch_bounds__(256, 3) void gemm_out(
    const unsigned short* __restrict__ A, const unsigned short* __restrict__ Bt,
    const float* __restrict__ bias, float* __restrict__ C) {
    constexpr int Kd = 1024;
    __shared__ __align__(16) unsigned short As[128 * 32];
    __shared__ __align__(16) unsigned short Bs[128 * 32];
    const int tid = threadIdx.x;
    const int l = tid & 63, w = tid >> 6;
    const int lr = l & 15, g = l >> 4;
    const int wr = w & 1, wc = w >> 1;
    const int m0 = blockIdx.y * 128, n0 = blockIdx.x * 128;

    f32x4 acc[4][4] = {};
    const int mr = tid >> 2;
    const int kk = (tid & 3) * 8;
    const unsigned short* a_src = A + (size_t)(m0 + mr) * Kd + kk;
    const unsigned short* b_src = Bt + (size_t)(n0 + mr) * Kd + kk;
    char* asb = (char*)As + w * 1024;
    char* bsb = (char*)Bs + w * 1024;

    for (int k0 = 0; k0 < Kd; k0 += 32) {
        __syncthreads();
        gload16(a_src + k0,           asb);
        gload16(a_src + 64 * Kd + k0, asb + 4096);
        gload16(b_src + k0,           bsb);
        gload16(b_src + 64 * Kd + k0, bsb + 4096);
        __syncthreads();
        bf16x8 av[4], bv[4];
#pragma unroll
        for (int mi = 0; mi < 4; mi++)
            av[mi] = lds_read8(&As[(wr * 64 + mi * 16 + lr) * 32 + g * 8]);
#pragma unroll
        for (int ni = 0; ni < 4; ni++)
            bv[ni] = lds_read8(&Bs[(wc * 64 + ni * 16 + lr) * 32 + g * 8]);
#pragma unroll
        for (int mi = 0; mi < 4; mi++)
#pragma unroll
            for (int ni = 0; ni < 4; ni++)
                acc[mi][ni] = mfma16(av[mi], bv[ni], acc[mi][ni]);
    }

#pragma unroll
    for (int ni = 0; ni < 4; ni++) {
        const int col = n0 + wc * 64 + ni * 16 + lr;
        const float bcol = bias[col];
#pragma unroll
        for (int mi = 0; mi < 4; mi++)
#pragma unroll
            for (int r = 0; r < 4; r++) {
                const int row = m0 + wr * 64 + mi * 16 + 4 * g + r;
                C[(size_t)row * D_ + col] = acc[mi][ni][r] + bcol;
            }
    }
}

// ------- flash attention (R8 config): swapped QK^T, fixed-shift softmax, dbuf -------
// q: [B][H][S][DK] bf16 (pre-scaled by 0.125*log2e), k: [B][H][S][DK],
// vT: [B][H][DK][S], mask: [B][S] int, aout: [B][S][D] bf16
__global__ __launch_bounds__(512, 4) void attn64(
    const unsigned short* __restrict__ q, const unsigned short* __restrict__ kmat,
    const unsigned short* __restrict__ vT, const int* __restrict__ mask,
    unsigned short* __restrict__ aout) {
    __shared__ __align__(16) unsigned short k_lds[2][64 * 64];  // [s_k][dk] XOR-swizzled
    __shared__ __align__(16) unsigned short v_lds[2][64 * 64];  // [dk][s_k] XOR-swizzled
    __shared__ __align__(16) unsigned short p_lds[8][16 * 72];  // per-wave P, +8 pad
    __shared__ int mflag;

    const int tid = threadIdx.x;
    const int l = tid & 63, w = tid >> 6;
    const int lr = l & 15, g = l >> 4;
    const int bh = blockIdx.y;
    const int b = bh >> 4, h = bh & 15;
    const int q0 = blockIdx.x * 128;

    const size_t base = (size_t)bh * S_ * DK_;
    const size_t vbase = (size_t)bh * DK_ * S_;
    const float FM = 14.0f;

    bf16x8 qf[2];
#pragma unroll
    for (int ks = 0; ks < 2; ks++)
        qf[ks] = __builtin_bit_cast(bf16x8,
            *(const u32x4*)(q + base + (size_t)(q0 + w * 16 + lr) * 64 + ks * 32 + g * 8));

    const u32x4 ones_u = {0x3F803F80u, 0x3F803F80u, 0x3F803F80u, 0x3F803F80u};
    const bf16x8 ones = __builtin_bit_cast(bf16x8, ones_u);

    f32x4 O[4] = {};
    f32x4 lrun = {};
    unsigned short* pw = &p_lds[w][0];

    const int srow = tid >> 3;
    const int ssl  = (tid & 7) ^ (srow & 7);
    const unsigned short* ksrc = kmat + base + (size_t)srow * DK_ + ssl * 8;
    const unsigned short* vsrc = vT + vbase + (size_t)srow * S_ + ssl * 8;
    const int* mrow = mask + b * S_;

    if (tid == 0) mflag = 0;
    gload16(ksrc, (char*)&k_lds[0][0] + w * 1024);
    gload16(vsrc, (char*)&v_lds[0][0] + w * 1024);
    int ok = 1;
#pragma unroll
    for (int i = 0; i < 4; i++) ok &= (mrow[tid + i * 512] != 0);
    __syncthreads();
    if (!__all(ok)) mflag = 1;
    __syncthreads();
    const int maskany = mflag;

    auto body = [&](int t, const unsigned short* kc, const unsigned short* vc,
                    char* kn, char* vn, bool pf) {
        const int kv0 = t * 64;
        if (pf) {
            gload16(ksrc + (size_t)(kv0 + 64) * DK_, kn + w * 1024);
            gload16(vsrc + (kv0 + 64),               vn + w * 1024);
        }

        f32x4 sacc[4];
        __builtin_amdgcn_s_setprio(1);
#pragma unroll
        for (int n = 0; n < 4; n++) {
            const int row = n * 16 + lr;
            const int x = lr & 7;
            bf16x8 kf0 = lds_read8(&kc[row * 64 + (g ^ x) * 8]);
            bf16x8 kf1 = lds_read8(&kc[row * 64 + ((4 + g) ^ x) * 8]);
            f32x4 s = {};
            s = mfma16(kf0, qf[0], s);
            s = mfma16(kf1, qf[1], s);
            sacc[n] = s;
        }
        __builtin_amdgcn_s_setprio(0);

        if (maskany) {
#pragma unroll
            for (int n = 0; n < 4; n++) {
                const int4 mm = *reinterpret_cast<const int4*>(&mrow[kv0 + n * 16 + 4 * g]);
                sacc[n][0] = mm.x ? sacc[n][0] : -3.0e8f;
                sacc[n][1] = mm.y ? sacc[n][1] : -3.0e8f;
                sacc[n][2] = mm.z ? sacc[n][2] : -3.0e8f;
                sacc[n][3] = mm.w ? sacc[n][3] : -3.0e8f;
            }
        }

#pragma unroll
        for (int n = 0; n < 4; n++) {
            const float e0 = exp2fast(sacc[n][0] - FM);
            const float e1 = exp2fast(sacc[n][1] - FM);
            const float e2 = exp2fast(sacc[n][2] - FM);
            const float e3 = exp2fast(sacc[n][3] - FM);
            uint2 pk;
            pk.x = cvtpk(e0, e1);
            pk.y = cvtpk(e2, e3);
            *reinterpret_cast<uint2*>(&pw[lr * 72 + n * 16 + 4 * g]) = pk;
        }

        f32x4 osum = {};
        __builtin_amdgcn_s_setprio(1);
#pragma unroll
        for (int k2 = 0; k2 < 2; k2++) {
            bf16x8 pa = lds_read8(&pw[lr * 72 + k2 * 32 + 8 * g]);
            osum = mfma16(pa, ones, osum);
#pragma unroll
            for (int n = 0; n < 4; n++) {
                const int row = n * 16 + lr;
                const int ph = (k2 * 4 + g) ^ (lr & 7);
                bf16x8 bvf = lds_read8(&vc[row * 64 + ph * 8]);
                O[n] = mfma16(pa, bvf, O[n]);
            }
        }
        __builtin_amdgcn_s_setprio(0);
        lrun += osum;

        __syncthreads();
    };

    for (int t = 0; t < S_ / 64; t += 2) {
        body(t,     &k_lds[0][0], &v_lds[0][0], (char*)&k_lds[1][0], (char*)&v_lds[1][0],
             true);
        body(t + 1, &k_lds[1][0], &v_lds[1][0], (char*)&k_lds[0][0], (char*)&v_lds[0][0],
             t + 2 < S_ / 64);
    }

#pragma unroll
    for (int r = 0; r < 4; r++) {
        const float inv = 1.0f / lrun[r];
        const int srw = q0 + w * 16 + 4 * g + r;
#pragma unroll
        for (int n = 0; n < 4; n++) {
            const int col = h * 64 + n * 16 + lr;
            aout[(size_t)(b * S_ + srw) * D_ + col] = f2bf(O[n][r] * inv);
        }
    }
}

extern "C" void kernel_launch(void* const* d_in, const int* in_sizes, int n_in,
                              void* d_out, int out_size, void* d_ws, size_t ws_size,
                              hipStream_t stream) {
    const float* Q  = (const float*)d_in[0];
    const float* K  = (const float*)d_in[1];
    const float* V  = (const float*)d_in[2];
    const float* Wq = (const float*)d_in[3];
    const float* bq = (const float*)d_in[4];
    const float* Wk = (const float*)d_in[5];
    const float* bk = (const float*)d_in[6];
    const float* Wv = (const float*)d_in[7];
    const float* bv = (const float*)d_in[8];
    const float* Wo = (const float*)d_in[9];
    const float* bo = (const float*)d_in[10];
    const int*   mk = (const int*)d_in[11];

    char* ws = (char*)d_ws;
    unsigned short* WqT = (unsigned short*)(ws + (24ull << 20));
    unsigned short* WkT = (unsigned short*)(ws + (26ull << 20));
    unsigned short* WvT = (unsigned short*)(ws + (28ull << 20));
    unsigned short* WoT = (unsigned short*)(ws + (30ull << 20));
    unsigned short* qb  = (unsigned short*)(ws + (32ull << 20));
    unsigned short* kb  = (unsigned short*)(ws + (40ull << 20));
    unsigned short* vTb = (unsigned short*)(ws + (48ull << 20));
    unsigned short* ab  = (unsigned short*)(ws + (56ull << 20));

    prep_w_kernel<<<4096, 256, 0, stream>>>(Wq, Wk, Wv, Wo, WqT, WkT, WvT, WoT);

    const float qs = 0.125f * 1.44269504088896340736f;  // 1/sqrt(DK) * log2(e)
    dim3 gq(8, 32, 3);
    qkv_gemm<<<gq, 256, 0, stream>>>(Q, K, V, WqT, WkT, WvT,
                                     bq, bk, bv, qb, kb, vTb, qs);

    dim3 ag(16, 32);
    attn64<<<ag, 512, 0, stream>>>(qb, kb, vTb, mk, ab);

    dim3 gg(8, 32);
    gemm_out<<<gg, 256, 0, stream>>>(ab, WoT, bo, (float*)d_out);
}

// Round 11
// 113.484 us; speedup vs baseline: 1.2276x; 1.2276x over previous
//
#include <hip/hip_runtime.h>
#include <hip/hip_bf16.h>
#include <cstdint>

#define B_ 2
#define S_ 2048
#define D_ 1024
#define H_ 16
#define DK_ 64

typedef __bf16 bf16x8 __attribute__((ext_vector_type(8)));
typedef float f32x4 __attribute__((ext_vector_type(4)));
typedef unsigned int u32x4 __attribute__((ext_vector_type(4)));

typedef __attribute__((address_space(3))) void lds_void_t;
typedef const __attribute__((address_space(1))) void gbl_void_t;

__device__ __forceinline__ unsigned short f2bf(float x) {
    unsigned int u = __builtin_bit_cast(unsigned int, x);
    u += 0x7fffu + ((u >> 16) & 1u);
    return (unsigned short)(u >> 16);
}

__device__ __forceinline__ float exp2fast(float x) {
    float r;
    asm("v_exp_f32 %0, %1" : "=v"(r) : "v"(x));
    return r;
}

__device__ __forceinline__ unsigned cvtpk(float a, float b) {
    unsigned r;
    asm("v_cvt_pk_bf16_f32 %0, %1, %2" : "=v"(r) : "v"(a), "v"(b));
    return r;
}

__device__ __forceinline__ void gload16(const void* g, void* lds) {
    __builtin_amdgcn_global_load_lds((gbl_void_t*)(uintptr_t)g,
                                     (lds_void_t*)(unsigned)(uintptr_t)lds,
                                     16, 0, 0);
}

__device__ __forceinline__ bf16x8 lds_read8(const unsigned short* p) {
    return __builtin_bit_cast(bf16x8, *(const u32x4*)p);
}

__device__ __forceinline__ f32x4 mfma16(bf16x8 a, bf16x8 b, f32x4 c) {
    return __builtin_amdgcn_mfma_f32_16x16x32_bf16(a, b, c, 0, 0, 0);
}

// ------- prep: cast+transpose W [K][N] fp32 -> Wt [N][K] bf16 (4 W's, x-decoded) -------
__global__ void prep_w_kernel(const float* __restrict__ Wq, const float* __restrict__ Wk,
                              const float* __restrict__ Wv, const float* __restrict__ Wo,
                              unsigned short* __restrict__ WqT, unsigned short* __restrict__ WkT,
                              unsigned short* __restrict__ WvT, unsigned short* __restrict__ WoT) {
    const int wsel = blockIdx.x >> 10;
    const int rem  = blockIdx.x & 1023;
    const int bx = rem & 31, by = rem >> 5;
    const float* W = (wsel == 0) ? Wq : (wsel == 1) ? Wk : (wsel == 2) ? Wv : Wo;
    unsigned short* Wt = (wsel == 0) ? WqT : (wsel == 1) ? WkT : (wsel == 2) ? WvT : WoT;
    __shared__ float t[32][33];
    const int tx = threadIdx.x & 31, ty = threadIdx.x >> 5;
#pragma unroll
    for (int j = 0; j < 4; j++)
        t[ty + 8 * j][tx] = W[(size_t)(by * 32 + ty + 8 * j) * D_ + bx * 32 + tx];
    __syncthreads();
#pragma unroll
    for (int j = 0; j < 4; j++)
        Wt[(size_t)(bx * 32 + ty + 8 * j) * D_ + by * 32 + tx] = f2bf(t[tx][ty + 8 * j]);
}

// -------- fused QKV projection GEMM with in-kernel fp32->bf16 A-cast, z selects --------
// XCD-swizzled: XCD c owns m-panels 4c..4c+3; the 8 n-blocks sharing an A-panel co-XCD.
__global__ __launch_bounds__(256, 3) void qkv_gemm(
    const float* __restrict__ Qf, const float* __restrict__ Kf,
    const float* __restrict__ Vf, const unsigned short* __restrict__ WqT,
    const unsigned short* __restrict__ WkT, const unsigned short* __restrict__ WvT,
    const float* __restrict__ bq, const float* __restrict__ bk,
    const float* __restrict__ bvv, unsigned short* __restrict__ qb,
    unsigned short* __restrict__ kb, unsigned short* __restrict__ vTb, float qs) {
    constexpr int Kd = 1024;
    __shared__ __align__(16) unsigned short As[128 * 32];
    __shared__ __align__(16) unsigned short Bs[128 * 32];
    __shared__ __align__(16) unsigned short Cs[128 * 136];  // z==2 transpose staging
    const int z = blockIdx.z;
    const float* Af = (z == 0) ? Qf : (z == 1) ? Kf : Vf;
    const unsigned short* Bt = (z == 0) ? WqT : (z == 1) ? WkT : WvT;
    const float* bias = (z == 0) ? bq : (z == 1) ? bk : bvv;
    const float cscale = (z == 0) ? qs : 1.0f;

    const int tid = threadIdx.x;
    const int l = tid & 63, w = tid >> 6;
    const int lr = l & 15, g = l >> 4;
    const int wr = w & 1, wc = w >> 1;

    // T1 XCD swizzle: XCD = wg%8 (dispatch round-robin); give it 4 m-panels, sweep n.
    const int wg  = blockIdx.x + 8 * blockIdx.y;   // 0..255
    const int eff = (wg & 7) * 32 + (wg >> 3);     // bijective (256 % 8 == 0)
    const int n0  = (eff & 7) * 128;
    const int m0  = (eff >> 3) * 128;

    f32x4 acc[4][4] = {};

    // A reg-staging geometry: thread covers rows arow+32i, cols acol..acol+3 (fp32)
    const int arow = tid >> 3;
    const int acol = (tid & 3) * 8 + ((tid >> 2) & 1) * 4;
    const float* a_base = Af + (size_t)(m0 + arow) * Kd + acol;

    const int mr = tid >> 2;
    const int kk = (tid & 3) * 8;
    const unsigned short* b_src = Bt + (size_t)(n0 + mr) * Kd + kk;
    char* bsb = (char*)Bs + w * 1024;

    float4 areg[4];
#pragma unroll
    for (int i = 0; i < 4; i++)
        areg[i] = *reinterpret_cast<const float4*>(a_base + (size_t)(32 * i) * Kd);

    for (int k0 = 0; k0 < Kd; k0 += 32) {
        __syncthreads();  // [1] prev compute done (As writable); drains A prefetch
        gload16(b_src + k0,           bsb);
        gload16(b_src + 64 * Kd + k0, bsb + 4096);
#pragma unroll
        for (int i = 0; i < 4; i++) {
            uint2 pk;
            pk.x = cvtpk(areg[i].x, areg[i].y);
            pk.y = cvtpk(areg[i].z, areg[i].w);
            *reinterpret_cast<uint2*>(&As[(arow + 32 * i) * 32 + acol]) = pk;
        }
        __syncthreads();  // [2] drains B gload (vmcnt) + A ds_writes (lgkm)
        if (k0 + 32 < Kd) {
#pragma unroll
            for (int i = 0; i < 4; i++)
                areg[i] = *reinterpret_cast<const float4*>(
                    a_base + (size_t)(32 * i) * Kd + k0 + 32);
        }
        bf16x8 av[4], bv[4];
#pragma unroll
        for (int mi = 0; mi < 4; mi++)
            av[mi] = lds_read8(&As[(wr * 64 + mi * 16 + lr) * 32 + g * 8]);
#pragma unroll
        for (int ni = 0; ni < 4; ni++)
            bv[ni] = lds_read8(&Bs[(wc * 64 + ni * 16 + lr) * 32 + g * 8]);
#pragma unroll
        for (int mi = 0; mi < 4; mi++)
#pragma unroll
            for (int ni = 0; ni < 4; ni++)
                acc[mi][ni] = mfma16(av[mi], bv[ni], acc[mi][ni]);
    }

    if (z == 2) {
#pragma unroll
        for (int ni = 0; ni < 4; ni++) {
            const int cl = wc * 64 + ni * 16 + lr;
            const float bcol = bias[n0 + cl];
#pragma unroll
            for (int mi = 0; mi < 4; mi++) {
                const int rw = wr * 64 + mi * 16 + 4 * g;
                uint2 pk;
                pk.x = cvtpk(acc[mi][ni][0] + bcol, acc[mi][ni][1] + bcol);
                pk.y = cvtpk(acc[mi][ni][2] + bcol, acc[mi][ni][3] + bcol);
                *reinterpret_cast<uint2*>(&Cs[cl * 136 + rw]) = pk;
            }
        }
        __syncthreads();
        const int s0g = m0 & 2047;
        const int bb  = m0 >> 11;
#pragma unroll
        for (int it = 0; it < 8; ++it) {
            const int cl = it * 16 + (tid >> 4);
            const int sc = tid & 15;
            const int cg = n0 + cl;
            const int hh = cg >> 6, dk = cg & 63;
            const u32x4 vv = *reinterpret_cast<const u32x4*>(&Cs[cl * 136 + sc * 8]);
            *reinterpret_cast<u32x4*>(
                &vTb[(((size_t)(bb * H_ + hh) * DK_ + dk) << 11) + s0g + sc * 8]) = vv;
        }
    } else {
#pragma unroll
        for (int ni = 0; ni < 4; ni++) {
            const int col = n0 + wc * 64 + ni * 16 + lr;
            const float bcol = bias[col];
#pragma unroll
            for (int mi = 0; mi < 4; mi++) {
#pragma unroll
                for (int r = 0; r < 4; r++) {
                    const int row = m0 + wr * 64 + mi * 16 + 4 * g + r;
                    const float v = (acc[mi][ni][r] + bcol) * cscale;
                    const int b = row >> 11, s = row & 2047, h = col >> 6, dk = col & 63;
                    unsigned short* out = z ? kb : qb;
                    out[(((size_t)(b * H_ + h) * S_ + s) << 6) + dk] = f2bf(v);
                }
            }
        }
    }
}

// ---------------- out-projection GEMM: fp32 out row-major, XCD-swizzled ----------------
__global__ __launch_bounds__(256, 3) void gemm_out(
    const unsigned short* __restrict__ A, const unsigned short* __restrict__ Bt,
    const float* __restrict__ bias, float* __restrict__ C) {
    constexpr int Kd = 1024;
    __shared__ __align__(16) unsigned short As[128 * 32];
    __shared__ __align__(16) unsigned short Bs[128 * 32];
    const int tid = threadIdx.x;
    const int l = tid & 63, w = tid >> 6;
    const int lr = l & 15, g = l >> 4;
    const int wr = w & 1, wc = w >> 1;

    const int wg  = blockIdx.x + 8 * blockIdx.y;   // 0..255
    const int eff = (wg & 7) * 32 + (wg >> 3);
    const int n0  = (eff & 7) * 128;
    const int m0  = (eff >> 3) * 128;

    f32x4 acc[4][4] = {};
    const int mr = tid >> 2;
    const int kk = (tid & 3) * 8;
    const unsigned short* a_src = A + (size_t)(m0 + mr) * Kd + kk;
    const unsigned short* b_src = Bt + (size_t)(n0 + mr) * Kd + kk;
    char* asb = (char*)As + w * 1024;
    char* bsb = (char*)Bs + w * 1024;

    for (int k0 = 0; k0 < Kd; k0 += 32) {
        __syncthreads();
        gload16(a_src + k0,           asb);
        gload16(a_src + 64 * Kd + k0, asb + 4096);
        gload16(b_src + k0,           bsb);
        gload16(b_src + 64 * Kd + k0, bsb + 4096);
        __syncthreads();
        bf16x8 av[4], bv[4];
#pragma unroll
        for (int mi = 0; mi < 4; mi++)
            av[mi] = lds_read8(&As[(wr * 64 + mi * 16 + lr) * 32 + g * 8]);
#pragma unroll
        for (int ni = 0; ni < 4; ni++)
            bv[ni] = lds_read8(&Bs[(wc * 64 + ni * 16 + lr) * 32 + g * 8]);
#pragma unroll
        for (int mi = 0; mi < 4; mi++)
#pragma unroll
            for (int ni = 0; ni < 4; ni++)
                acc[mi][ni] = mfma16(av[mi], bv[ni], acc[mi][ni]);
    }

#pragma unroll
    for (int ni = 0; ni < 4; ni++) {
        const int col = n0 + wc * 64 + ni * 16 + lr;
        const float bcol = bias[col];
#pragma unroll
        for (int mi = 0; mi < 4; mi++)
#pragma unroll
            for (int r = 0; r < 4; r++) {
                const int row = m0 + wr * 64 + mi * 16 + 4 * g + r;
                C[(size_t)row * D_ + col] = acc[mi][ni][r] + bcol;
            }
    }
}

// ------- flash attention (R8 config + XCD swizzle): swapped QK^T, fixed-shift SM -------
__global__ __launch_bounds__(512, 4) void attn64(
    const unsigned short* __restrict__ q, const unsigned short* __restrict__ kmat,
    const unsigned short* __restrict__ vT, const int* __restrict__ mask,
    unsigned short* __restrict__ aout) {
    __shared__ __align__(16) unsigned short k_lds[2][64 * 64];
    __shared__ __align__(16) unsigned short v_lds[2][64 * 64];
    __shared__ __align__(16) unsigned short p_lds[8][16 * 72];
    __shared__ int mflag;

    const int tid = threadIdx.x;
    const int l = tid & 63, w = tid >> 6;
    const int lr = l & 15, g = l >> 4;

    // T1 XCD swizzle: XCD c owns bh 4c..4c+3 (K/V 2MB -> L2-resident), 16 q-tiles co-XCD
    const int wg  = blockIdx.x + 16 * blockIdx.y;  // 0..511
    const int eff = (wg & 7) * 64 + (wg >> 3);     // bijective (512 % 8 == 0)
    const int q0  = (eff & 15) * 128;
    const int bh  = eff >> 4;
    const int b = bh >> 4, h = bh & 15;

    const size_t base = (size_t)bh * S_ * DK_;
    const size_t vbase = (size_t)bh * DK_ * S_;
    const float FM = 14.0f;

    bf16x8 qf[2];
#pragma unroll
    for (int ks = 0; ks < 2; ks++)
        qf[ks] = __builtin_bit_cast(bf16x8,
            *(const u32x4*)(q + base + (size_t)(q0 + w * 16 + lr) * 64 + ks * 32 + g * 8));

    const u32x4 ones_u = {0x3F803F80u, 0x3F803F80u, 0x3F803F80u, 0x3F803F80u};
    const bf16x8 ones = __builtin_bit_cast(bf16x8, ones_u);

    f32x4 O[4] = {};
    f32x4 lrun = {};
    unsigned short* pw = &p_lds[w][0];

    const int srow = tid >> 3;
    const int ssl  = (tid & 7) ^ (srow & 7);
    const unsigned short* ksrc = kmat + base + (size_t)srow * DK_ + ssl * 8;
    const unsigned short* vsrc = vT + vbase + (size_t)srow * S_ + ssl * 8;
    const int* mrow = mask + b * S_;

    if (tid == 0) mflag = 0;
    gload16(ksrc, (char*)&k_lds[0][0] + w * 1024);
    gload16(vsrc, (char*)&v_lds[0][0] + w * 1024);
    int ok = 1;
#pragma unroll
    for (int i = 0; i < 4; i++) ok &= (mrow[tid + i * 512] != 0);
    __syncthreads();
    if (!__all(ok)) mflag = 1;
    __syncthreads();
    const int maskany = mflag;

    auto body = [&](int t, const unsigned short* kc, const unsigned short* vc,
                    char* kn, char* vn, bool pf) {
        const int kv0 = t * 64;
        if (pf) {
            gload16(ksrc + (size_t)(kv0 + 64) * DK_, kn + w * 1024);
            gload16(vsrc + (kv0 + 64),               vn + w * 1024);
        }

        f32x4 sacc[4];
        __builtin_amdgcn_s_setprio(1);
#pragma unroll
        for (int n = 0; n < 4; n++) {
            const int row = n * 16 + lr;
            const int x = lr & 7;
            bf16x8 kf0 = lds_read8(&kc[row * 64 + (g ^ x) * 8]);
            bf16x8 kf1 = lds_read8(&kc[row * 64 + ((4 + g) ^ x) * 8]);
            f32x4 s = {};
            s = mfma16(kf0, qf[0], s);
            s = mfma16(kf1, qf[1], s);
            sacc[n] = s;
        }
        __builtin_amdgcn_s_setprio(0);

        if (maskany) {
#pragma unroll
            for (int n = 0; n < 4; n++) {
                const int4 mm = *reinterpret_cast<const int4*>(&mrow[kv0 + n * 16 + 4 * g]);
                sacc[n][0] = mm.x ? sacc[n][0] : -3.0e8f;
                sacc[n][1] = mm.y ? sacc[n][1] : -3.0e8f;
                sacc[n][2] = mm.z ? sacc[n][2] : -3.0e8f;
                sacc[n][3] = mm.w ? sacc[n][3] : -3.0e8f;
            }
        }

#pragma unroll
        for (int n = 0; n < 4; n++) {
            const float e0 = exp2fast(sacc[n][0] - FM);
            const float e1 = exp2fast(sacc[n][1] - FM);
            const float e2 = exp2fast(sacc[n][2] - FM);
            const float e3 = exp2fast(sacc[n][3] - FM);
            uint2 pk;
            pk.x = cvtpk(e0, e1);
            pk.y = cvtpk(e2, e3);
            *reinterpret_cast<uint2*>(&pw[lr * 72 + n * 16 + 4 * g]) = pk;
        }

        f32x4 osum = {};
        __builtin_amdgcn_s_setprio(1);
#pragma unroll
        for (int k2 = 0; k2 < 2; k2++) {
            bf16x8 pa = lds_read8(&pw[lr * 72 + k2 * 32 + 8 * g]);
            osum = mfma16(pa, ones, osum);
#pragma unroll
            for (int n = 0; n < 4; n++) {
                const int row = n * 16 + lr;
                const int ph = (k2 * 4 + g) ^ (lr & 7);
                bf16x8 bvf = lds_read8(&vc[row * 64 + ph * 8]);
                O[n] = mfma16(pa, bvf, O[n]);
            }
        }
        __builtin_amdgcn_s_setprio(0);
        lrun += osum;

        __syncthreads();
    };

    for (int t = 0; t < S_ / 64; t += 2) {
        body(t,     &k_lds[0][0], &v_lds[0][0], (char*)&k_lds[1][0], (char*)&v_lds[1][0],
             true);
        body(t + 1, &k_lds[1][0], &v_lds[1][0], (char*)&k_lds[0][0], (char*)&v_lds[0][0],
             t + 2 < S_ / 64);
    }

#pragma unroll
    for (int r = 0; r < 4; r++) {
        const float inv = 1.0f / lrun[r];
        const int srw = q0 + w * 16 + 4 * g + r;
#pragma unroll
        for (int n = 0; n < 4; n++) {
            const int col = h * 64 + n * 16 + lr;
            aout[(size_t)(b * S_ + srw) * D_ + col] = f2bf(O[n][r] * inv);
        }
    }
}

extern "C" void kernel_launch(void* const* d_in, const int* in_sizes, int n_in,
                              void* d_out, int out_size, void* d_ws, size_t ws_size,
                              hipStream_t stream) {
    const float* Q  = (const float*)d_in[0];
    const float* K  = (const float*)d_in[1];
    const float* V  = (const float*)d_in[2];
    const float* Wq = (const float*)d_in[3];
    const float* bq = (const float*)d_in[4];
    const float* Wk = (const float*)d_in[5];
    const float* bk = (const float*)d_in[6];
    const float* Wv = (const float*)d_in[7];
    const float* bv = (const float*)d_in[8];
    const float* Wo = (const float*)d_in[9];
    const float* bo = (const float*)d_in[10];
    const int*   mk = (const int*)d_in[11];

    char* ws = (char*)d_ws;
    unsigned short* WqT = (unsigned short*)(ws + (24ull << 20));
    unsigned short* WkT = (unsigned short*)(ws + (26ull << 20));
    unsigned short* WvT = (unsigned short*)(ws + (28ull << 20));
    unsigned short* WoT = (unsigned short*)(ws + (30ull << 20));
    unsigned short* qb  = (unsigned short*)(ws + (32ull << 20));
    unsigned short* kb  = (unsigned short*)(ws + (40ull << 20));
    unsigned short* vTb = (unsigned short*)(ws + (48ull << 20));
    unsigned short* ab  = (unsigned short*)(ws + (56ull << 20));

    prep_w_kernel<<<4096, 256, 0, stream>>>(Wq, Wk, Wv, Wo, WqT, WkT, WvT, WoT);

    const float qs = 0.125f * 1.44269504088896340736f;  // 1/sqrt(DK) * log2(e)
    dim3 gq(8, 32, 3);
    qkv_gemm<<<gq, 256, 0, stream>>>(Q, K, V, WqT, WkT, WvT,
                                     bq, bk, bv, qb, kb, vTb, qs);

    dim3 ag(16, 32);
    attn64<<<ag, 512, 0, stream>>>(qb, kb, vTb, mk, ab);

    dim3 gg(8, 32);
    gemm_out<<<gg, 256, 0, stream>>>(ab, WoT, bo, (float*)d_out);
}